// Round 7
// baseline (153.292 us; speedup 1.0000x reference)
//
#include <hip/hip_runtime.h>
#include <math.h>

#define N_NODES 1024
#define F_DIM   128
#define M_DIM   256
#define E_DIM   8
#define P_PAIRS 523776   // N*(N-1)/2
#define NBLK    1056     // sum_{tj=0..31} (2*tj+2) 16x32 tiles

// ---------- Kernel A: pa/pb projections (+cterm folded) + stress; block 128 = BN fold ----------
__global__ __launch_bounds__(256) void kA(const float* __restrict__ x,
                                          const float* __restrict__ ctx,
                                          const float* __restrict__ W1,
                                          const float* __restrict__ b1,
                                          const float* __restrict__ gamma,
                                          const float* __restrict__ beta,
                                          const float* __restrict__ rmean,
                                          const float* __restrict__ rvar,
                                          const float* __restrict__ W2,
                                          const float* __restrict__ b2,
                                          float* __restrict__ pa,
                                          float* __restrict__ pb,
                                          float* __restrict__ stress,
                                          float* __restrict__ w2ft,
                                          float* __restrict__ b2f) {
  const int t = threadIdx.x;

  if (blockIdx.x == 128) {
    __shared__ float bnbs[256];
    const float s   = gamma[t] / sqrtf(rvar[t] + 1e-5f);
    bnbs[t] = beta[t] - s * rmean[t];
    #pragma unroll
    for (int e = 0; e < 8; ++e) w2ft[t * 8 + e] = W2[e * 256 + t] * s;
    __syncthreads();
    const int wv = t >> 6, lane = t & 63;
    #pragma unroll
    for (int r = 0; r < 2; ++r) {
      const int e = wv * 2 + r;
      float acc = 0.f;
      #pragma unroll
      for (int k = 0; k < 4; ++k) acc += W2[e * 256 + lane + 64 * k] * bnbs[lane + 64 * k];
      #pragma unroll
      for (int m = 32; m > 0; m >>= 1) acc += __shfl_xor(acc, m, 64);
      if (lane == 0) b2f[e] = acc + b2[e];
    }
    return;
  }

  __shared__ float xv[8][128];
  const int n0 = blockIdx.x * 8;
  ((float4*)&xv[0][0])[t] = ((const float4*)(x + (size_t)n0 * F_DIM))[t];  // 8 rows
  __syncthreads();

  // stress (torch unbiased std): 4 waves x 2 nodes, same per-lane order as before
  {
    const int wv = t >> 6, lane = t & 63;
    #pragma unroll
    for (int r = 0; r < 2; ++r) {
      const int nn = wv * 2 + r;
      const float a = xv[nn][lane], b = xv[nn][lane + 64];
      float sum = a + b;
      #pragma unroll
      for (int m = 32; m > 0; m >>= 1) sum += __shfl_xor(sum, m, 64);
      const float mean = sum * (1.0f / 128.0f);
      const float d0 = a - mean, d1 = b - mean;
      float ss = d0 * d0 + d1 * d1;
      #pragma unroll
      for (int m = 32; m > 0; m >>= 1) ss += __shfl_xor(ss, m, 64);
      if (lane == 0) stress[n0 + nn] = sqrtf(ss * (1.0f / 127.0f));
    }
  }

  const float4* wrow = (const float4*)(W1 + (size_t)t * 260);  // W1 row-major [256][260]
  float accA[8] = {0.f, 0.f, 0.f, 0.f, 0.f, 0.f, 0.f, 0.f};
  float accB[8] = {0.f, 0.f, 0.f, 0.f, 0.f, 0.f, 0.f, 0.f};
  #pragma unroll 4
  for (int k4 = 0; k4 < 32; ++k4) {
    const float4 wa = wrow[k4];
    const float4 wb = wrow[32 + k4];
    #pragma unroll
    for (int nn = 0; nn < 8; ++nn) {
      const float4 xf = ((const float4*)&xv[nn][0])[k4];
      accA[nn] = fmaf(xf.w, wa.w, fmaf(xf.z, wa.z, fmaf(xf.y, wa.y, fmaf(xf.x, wa.x, accA[nn]))));
      accB[nn] = fmaf(xf.w, wb.w, fmaf(xf.z, wb.z, fmaf(xf.y, wb.y, fmaf(xf.x, wb.x, accB[nn]))));
    }
  }
  const float c0 = ctx[0], c1 = ctx[1], c2 = ctx[2], c3 = ctx[3];
  const float* rowt = W1 + (size_t)t * 260 + 256;
  const float ctv = b1[t] + c0 * rowt[0] + c1 * rowt[1] + c2 * rowt[2] + c3 * rowt[3];
  #pragma unroll
  for (int nn = 0; nn < 8; ++nn) {
    pa[(size_t)(n0 + nn) * M_DIM + t] = accA[nn] + ctv;   // cterm folded (bit-exact)
    pb[(size_t)(n0 + nn) * M_DIM + t] = accB[nn];
  }
}

// ---------- Kernel C: 1056 triangular 16x32 tiles, 128 threads, 2x2 micro-tile ----------
// w2ft loads forced to VECTOR global_load (opaque-zero VGPR index defeats scalarization)
// -> vmcnt domain, double-buffered one m4 ahead. ds_read tile loads pipelined one m4
// ahead on lgkmcnt. The two latency domains decouple; waits land after 160-FMA blocks.
__global__ __launch_bounds__(128, 3) void kC(const float* __restrict__ pa,
                                             const float* __restrict__ pb,
                                             const float* __restrict__ w2ft,
                                             const float* __restrict__ b2f,
                                             const float* __restrict__ W3,
                                             const float* __restrict__ b3,
                                             const float* __restrict__ stress,
                                             float* __restrict__ out) {
  __shared__ float4 a4[16 * 32];   // 16 i-rows x 32 float4 (128-m chunk), col rotated by row
  __shared__ float4 b4[32 * 32];   // 32 j-rows
  const int t = threadIdx.x;       // 0..127

  // decode p -> (tj, si): p = tj*(tj+1) + si, si in [0, 2*tj+2)
  const int p = blockIdx.x;
  int tj = (int)((sqrtf(4.0f * (float)p + 1.0f) - 1.0f) * 0.5f);
  while ((tj + 1) * (tj + 2) <= p) ++tj;
  while (tj * (tj + 1) > p) --tj;
  const int si = p - tj * (tj + 1);
  const int i0 = si * 16, j0 = tj * 32;

  // stressed-node mean (same per-lane reduction order as rounds 3-6)
  float ssum = 0.f;
  {
    const int lane = t & 63;
    #pragma unroll
    for (int k = 0; k < 16; ++k) ssum += stress[lane + 64 * k];
    #pragma unroll
    for (int m = 32; m > 0; m >>= 1) ssum += __shfl_xor(ssum, m, 64);
  }
  const float smean = ssum * (1.0f / 1024.0f);

  // opaque zero in a VGPR: compiler cannot prove w loads uniform -> keeps them VMEM
  int zr;
  asm volatile("v_mov_b32 %0, 0" : "=v"(zr));
  const float4* w4v = ((const float4*)w2ft) + zr;

  const int jx = t & 15;   // j in tile: jx, jx+16
  const int iy = t >> 4;   // i in tile: iy, iy+8  (0..7)
  float acc[4][8];         // [ia*2+jb][e]: (iy,jx),(iy,jx+16),(iy+8,jx),(iy+8,jx+16)
  #pragma unroll
  for (int q = 0; q < 4; ++q)
    #pragma unroll
    for (int e = 0; e < 8; ++e) acc[q][e] = 0.f;

  const float4* pa4 = (const float4*)pa;
  const float4* pb4 = (const float4*)pb;

  auto stage = [&](int cb) {
    float4 rg[12];
    #pragma unroll
    for (int q = 0; q < 12; ++q) {
      if (q < 4) {
        const int d = q * 128 + t, r = d >> 5, c = ((d & 31) - r) & 31;
        rg[q] = pa4[(size_t)(i0 + r) * 64 + cb * 32 + c];
      } else {
        const int d2 = (q - 4) * 128 + t, r = d2 >> 5, c = ((d2 & 31) - r) & 31;
        rg[q] = pb4[(size_t)(j0 + r) * 64 + cb * 32 + c];
      }
    }
    #pragma unroll
    for (int q = 0; q < 12; ++q) {
      if (q < 4) a4[q * 128 + t] = rg[q];
      else       b4[(q - 4) * 128 + t] = rg[q];
    }
  };

  auto computeChunk = [&](int cw) {
    float4 wc[8], wn[8];
    #pragma unroll
    for (int q = 0; q < 8; ++q) wc[q] = w4v[cw * 8 + q];
    float4 A0 = a4[iy * 32 + (iy & 31)];
    float4 A1 = a4[(iy + 8) * 32 + ((iy + 8) & 31)];
    float4 B0 = b4[jx * 32 + (jx & 31)];
    float4 B1 = b4[(jx + 16) * 32 + ((jx + 16) & 31)];
    for (int m4 = 0; m4 < 32; ++m4) {
      float4 An0, An1, Bn0, Bn1;
      if (m4 < 31) {
        #pragma unroll
        for (int q = 0; q < 8; ++q) wn[q] = w4v[(cw + m4 + 1) * 8 + q];  // vmcnt prefetch
        const int mn = m4 + 1;
        An0 = a4[iy * 32 + ((mn + iy) & 31)];                             // lgkm prefetch
        An1 = a4[(iy + 8) * 32 + ((mn + iy + 8) & 31)];
        Bn0 = b4[jx * 32 + ((mn + jx) & 31)];
        Bn1 = b4[(jx + 16) * 32 + ((mn + jx + 16) & 31)];
      }
      const float* a0f = (const float*)&A0;
      const float* a1f = (const float*)&A1;
      const float* b0f = (const float*)&B0;
      const float* b1f = (const float*)&B1;
      #pragma unroll
      for (int mm = 0; mm < 4; ++mm) {
        const float r00 = fmaxf(a0f[mm] + b0f[mm], 0.f);
        const float r01 = fmaxf(a0f[mm] + b1f[mm], 0.f);
        const float r10 = fmaxf(a1f[mm] + b0f[mm], 0.f);
        const float r11 = fmaxf(a1f[mm] + b1f[mm], 0.f);
        const float* wl = (const float*)&wc[mm * 2];      // e 0..3
        const float* wh = (const float*)&wc[mm * 2 + 1];  // e 4..7
        #pragma unroll
        for (int e = 0; e < 4; ++e) {
          acc[0][e]     = fmaf(wl[e], r00, acc[0][e]);
          acc[1][e]     = fmaf(wl[e], r01, acc[1][e]);
          acc[2][e]     = fmaf(wl[e], r10, acc[2][e]);
          acc[3][e]     = fmaf(wl[e], r11, acc[3][e]);
          acc[0][e + 4] = fmaf(wh[e], r00, acc[0][e + 4]);
          acc[1][e + 4] = fmaf(wh[e], r01, acc[1][e + 4]);
          acc[2][e + 4] = fmaf(wh[e], r10, acc[2][e + 4]);
          acc[3][e + 4] = fmaf(wh[e], r11, acc[3][e + 4]);
        }
      }
      if (m4 < 31) {
        #pragma unroll
        for (int q = 0; q < 8; ++q) wc[q] = wn[q];
        A0 = An0; A1 = An1; B0 = Bn0; B1 = Bn1;
      }
    }
  };

  stage(0);
  __syncthreads();
  computeChunk(0);
  __syncthreads();
  stage(1);
  __syncthreads();
  computeChunk(32);

  // ---- epilogue ----
  float w3v[8], b2v[8];
  #pragma unroll
  for (int e = 0; e < 8; ++e) { w3v[e] = W3[e]; b2v[e] = b2f[e]; }
  const float b3v = b3[0];
  #pragma unroll
  for (int ia = 0; ia < 2; ++ia) {
    #pragma unroll
    for (int jb = 0; jb < 2; ++jb) {
      const int i = i0 + iy + ia * 8;
      const int j = j0 + jx + jb * 16;
      if (i < j) {
        const int q = ia * 2 + jb;
        float logit = b3v;
        #pragma unroll
        for (int e = 0; e < 8; ++e) {
          const float h2 = fmaxf(acc[q][e] + b2v[e], 0.f);
          logit = fmaf(w3v[e], h2, logit);
        }
        const float score = 1.0f / (1.0f + expf(-logit));
        const int idx = i * 1023 - (i * (i - 1)) / 2 + (j - i - 1);
        out[idx] = score;
        const bool mk = (score > 0.5f) && (stress[i] > smean) && (stress[j] > smean);
        out[P_PAIRS + idx] = mk ? 1.0f : 0.0f;
      }
    }
  }
}

extern "C" void kernel_launch(void* const* d_in, const int* in_sizes, int n_in,
                              void* d_out, int out_size, void* d_ws, size_t ws_size,
                              hipStream_t stream) {
  const float* x     = (const float*)d_in[0];
  const float* ctx   = (const float*)d_in[1];
  const float* W1    = (const float*)d_in[2];
  const float* b1    = (const float*)d_in[3];
  const float* gamma = (const float*)d_in[4];
  const float* beta  = (const float*)d_in[5];
  const float* rmean = (const float*)d_in[6];
  const float* rvar  = (const float*)d_in[7];
  const float* W2    = (const float*)d_in[8];
  const float* b2    = (const float*)d_in[9];
  const float* W3    = (const float*)d_in[10];
  const float* b3    = (const float*)d_in[11];
  float* out = (float*)d_out;

  float* ws     = (float*)d_ws;
  float* pa     = ws;              // 1024*256 (cterm pre-folded)
  float* pb     = pa + 262144;     // 1024*256
  float* w2ft   = pb + 262144;     // 256*8 (transposed [m][e], BN-scaled)
  float* b2f    = w2ft + 2048;     // 8
  float* stress = b2f + 8;         // 1024

  hipLaunchKernelGGL(kA, dim3(129), dim3(256), 0, stream, x, ctx, W1, b1, gamma, beta,
                     rmean, rvar, W2, b2, pa, pb, stress, w2ft, b2f);
  hipLaunchKernelGGL(kC, dim3(NBLK), dim3(128), 0, stream, pa, pb, w2ft, b2f,
                     W3, b3, stress, out);
}

// Round 8
// 124.396 us; speedup vs baseline: 1.2323x; 1.2323x over previous
//
#include <hip/hip_runtime.h>
#include <math.h>

#define N_NODES 1024
#define F_DIM   128
#define M_DIM   256
#define E_DIM   8
#define P_PAIRS 523776   // N*(N-1)/2
#define NBLK    1056     // sum_{tj=0..31} (2*tj+2) 16x32 tiles
#define APITCH  33       // padded row pitch in float4 (bank-decorrelating)

typedef float v2f __attribute__((ext_vector_type(2)));

#if defined(__has_builtin)
#if __has_builtin(__builtin_elementwise_fma)
#define PK_FMA(a, b, c) __builtin_elementwise_fma((a), (b), (c))
#endif
#endif
#ifndef PK_FMA
static __device__ inline v2f pk_fma_fallback(v2f a, v2f b, v2f c) {
  v2f r;
  r.x = fmaf(a.x, b.x, c.x);
  r.y = fmaf(a.y, b.y, c.y);
  return r;
}
#define PK_FMA(a, b, c) pk_fma_fallback((a), (b), (c))
#endif

// ---------- Kernel A: pa/pb projections (+cterm folded) + stress; block 256 = BN fold ----------
__global__ __launch_bounds__(256) void kA(const float* __restrict__ x,
                                          const float* __restrict__ ctx,
                                          const float* __restrict__ W1,
                                          const float* __restrict__ b1,
                                          const float* __restrict__ gamma,
                                          const float* __restrict__ beta,
                                          const float* __restrict__ rmean,
                                          const float* __restrict__ rvar,
                                          const float* __restrict__ W2,
                                          const float* __restrict__ b2,
                                          float* __restrict__ pa,
                                          float* __restrict__ pb,
                                          float* __restrict__ stress,
                                          float* __restrict__ w2ft,
                                          float* __restrict__ b2f) {
  const int t = threadIdx.x;

  if (blockIdx.x == 256) {
    __shared__ float bnbs[256];
    const float s   = gamma[t] / sqrtf(rvar[t] + 1e-5f);
    bnbs[t] = beta[t] - s * rmean[t];
    #pragma unroll
    for (int e = 0; e < 8; ++e) w2ft[t * 8 + e] = W2[e * 256 + t] * s;
    __syncthreads();
    const int wv = t >> 6, lane = t & 63;
    #pragma unroll
    for (int r = 0; r < 2; ++r) {
      const int e = wv * 2 + r;
      float acc = 0.f;
      #pragma unroll
      for (int k = 0; k < 4; ++k) acc += W2[e * 256 + lane + 64 * k] * bnbs[lane + 64 * k];
      #pragma unroll
      for (int m = 32; m > 0; m >>= 1) acc += __shfl_xor(acc, m, 64);
      if (lane == 0) b2f[e] = acc + b2[e];
    }
    return;
  }

  __shared__ float xv[4][128];
  const int n0 = blockIdx.x * 4;
  if (t < 128) {
    ((float4*)&xv[0][0])[t] = ((const float4*)(x + (size_t)n0 * F_DIM))[t];
  }
  __syncthreads();

  {
    const int wv = t >> 6, lane = t & 63;
    const float a = xv[wv][lane], b = xv[wv][lane + 64];
    float sum = a + b;
    #pragma unroll
    for (int m = 32; m > 0; m >>= 1) sum += __shfl_xor(sum, m, 64);
    const float mean = sum * (1.0f / 128.0f);
    const float d0 = a - mean, d1 = b - mean;
    float ss = d0 * d0 + d1 * d1;
    #pragma unroll
    for (int m = 32; m > 0; m >>= 1) ss += __shfl_xor(ss, m, 64);
    if (lane == 0) stress[n0 + wv] = sqrtf(ss * (1.0f / 127.0f));
  }

  const float4* wrow = (const float4*)(W1 + (size_t)t * 260);  // W1 row-major [256][260]
  float accA[4] = {0.f, 0.f, 0.f, 0.f};
  float accB[4] = {0.f, 0.f, 0.f, 0.f};
  #pragma unroll 8
  for (int k4 = 0; k4 < 32; ++k4) {
    const float4 wa = wrow[k4];
    const float4 wb = wrow[32 + k4];
    #pragma unroll
    for (int nn = 0; nn < 4; ++nn) {
      const float4 xf = ((const float4*)&xv[nn][0])[k4];
      accA[nn] = fmaf(xf.w, wa.w, fmaf(xf.z, wa.z, fmaf(xf.y, wa.y, fmaf(xf.x, wa.x, accA[nn]))));
      accB[nn] = fmaf(xf.w, wb.w, fmaf(xf.z, wb.z, fmaf(xf.y, wb.y, fmaf(xf.x, wb.x, accB[nn]))));
    }
  }
  const float c0 = ctx[0], c1 = ctx[1], c2 = ctx[2], c3 = ctx[3];
  const float* rowt = W1 + (size_t)t * 260 + 256;
  const float ctv = b1[t] + c0 * rowt[0] + c1 * rowt[1] + c2 * rowt[2] + c3 * rowt[3];
  #pragma unroll
  for (int nn = 0; nn < 4; ++nn) {
    pa[(size_t)(n0 + nn) * M_DIM + t] = accA[nn] + ctv;   // cterm folded (bit-exact)
    pb[(size_t)(n0 + nn) * M_DIM + t] = accB[nn];
  }
}

// ---------- Kernel C: 1056 triangular 16x32 tiles, 256 threads, 2 pairs/thread ----------
// LDS rows padded to 33 float4 -> compute reads are 2-way max (free) with LINEAR
// addressing: base hoisted, m4*16B immediate offsets (no per-iter addr VALU, compiler
// batches ds_reads with fine-grained lgkmcnt). Accumulate with v_pk_fma_f32 (packed
// fp32; per-e chains bit-identical). w2ft via wave-uniform s_load.
__global__ __launch_bounds__(256, 4) void kC(const float* __restrict__ pa,
                                             const float* __restrict__ pb,
                                             const float* __restrict__ w2ft,
                                             const float* __restrict__ b2f,
                                             const float* __restrict__ W3,
                                             const float* __restrict__ b3,
                                             const float* __restrict__ stress,
                                             float* __restrict__ out) {
  __shared__ float4 a4[16 * APITCH];   // 16 i-rows, 128-m chunk, pitch 33
  __shared__ float4 b4[32 * APITCH];   // 32 j-rows
  const int t = threadIdx.x;

  // decode p -> (tj, si): p = tj*(tj+1) + si, si in [0, 2*tj+2)
  const int p = blockIdx.x;
  int tj = (int)((sqrtf(4.0f * (float)p + 1.0f) - 1.0f) * 0.5f);
  while ((tj + 1) * (tj + 2) <= p) ++tj;
  while (tj * (tj + 1) > p) --tj;
  const int si = p - tj * (tj + 1);
  const int i0 = si * 16, j0 = tj * 32;

  // stressed-node mean (same per-lane reduction order as rounds 3-7)
  float ssum = 0.f;
  {
    const int lane = t & 63;
    #pragma unroll
    for (int k = 0; k < 16; ++k) ssum += stress[lane + 64 * k];
    #pragma unroll
    for (int m = 32; m > 0; m >>= 1) ssum += __shfl_xor(ssum, m, 64);
  }
  const float smean = ssum * (1.0f / 1024.0f);

  const int jx = t & 15;   // j within tile: jx, jx+16
  const int iy = t >> 4;   // i within tile, 0..15
  v2f acc[2][4];           // [pair][e-pair]: e(2k),e(2k+1) packed
  #pragma unroll
  for (int q = 0; q < 2; ++q)
    #pragma unroll
    for (int k = 0; k < 4; ++k) acc[q][k] = (v2f){0.f, 0.f};

  const float4* pa4 = (const float4*)pa;
  const float4* pb4 = (const float4*)pb;
  const float4* w4g = (const float4*)w2ft;

  float4 rg[6];

  // ---- stage chunk 0 (a: slots 0..511, b: slots 0..1023) ----
  #pragma unroll
  for (int q = 0; q < 6; ++q) {
    if (q < 2) {
      const int d = q * 256 + t, r = d >> 5, c = d & 31;
      rg[q] = pa4[(size_t)(i0 + r) * 64 + c];
    } else {
      const int d2 = (q - 2) * 256 + t, r = d2 >> 5, c = d2 & 31;
      rg[q] = pb4[(size_t)(j0 + r) * 64 + c];
    }
  }
  #pragma unroll
  for (int q = 0; q < 6; ++q) {
    if (q < 2) {
      const int d = q * 256 + t, r = d >> 5, c = d & 31;
      a4[r * APITCH + c] = rg[q];
    } else {
      const int d2 = (q - 2) * 256 + t, r = d2 >> 5, c = d2 & 31;
      b4[r * APITCH + c] = rg[q];
    }
  }
  __syncthreads();

  // ---- prefetch chunk 1 into registers (in flight during chunk-0 compute) ----
  #pragma unroll
  for (int q = 0; q < 6; ++q) {
    if (q < 2) {
      const int d = q * 256 + t, r = d >> 5, c = d & 31;
      rg[q] = pa4[(size_t)(i0 + r) * 64 + 32 + c];
    } else {
      const int d2 = (q - 2) * 256 + t, r = d2 >> 5, c = d2 & 31;
      rg[q] = pb4[(size_t)(j0 + r) * 64 + 32 + c];
    }
  }

  const float4* aRow  = a4 + iy * APITCH;          // bases hoisted; m4 offsets immediate
  const float4* bRow0 = b4 + jx * APITCH;
  const float4* bRow1 = b4 + (jx + 16) * APITCH;

  auto computeChunk = [&](int cw) {
    #pragma unroll 4
    for (int m4 = 0; m4 < 32; ++m4) {
      const float4 a0 = aRow[m4];
      const float4 b0 = bRow0[m4];
      const float4 b1 = bRow1[m4];
      float4 wc[8];
      #pragma unroll
      for (int q = 0; q < 8; ++q) wc[q] = w4g[(cw + m4) * 8 + q];  // uniform -> s_load

      const float* a0f = (const float*)&a0;
      const float* b0f = (const float*)&b0;
      const float* b1f = (const float*)&b1;
      #pragma unroll
      for (int mm = 0; mm < 4; ++mm) {
        const float r0 = fmaxf(a0f[mm] + b0f[mm], 0.f);
        const float r1 = fmaxf(a0f[mm] + b1f[mm], 0.f);
        const v2f rr0 = {r0, r0};
        const v2f rr1 = {r1, r1};
        const v2f* wp = (const v2f*)&wc[mm * 2];   // 4 v2f covering e 0..7
        #pragma unroll
        for (int k = 0; k < 4; ++k) {
          acc[0][k] = PK_FMA(wp[k], rr0, acc[0][k]);
          acc[1][k] = PK_FMA(wp[k], rr1, acc[1][k]);
        }
      }
    }
  };

  computeChunk(0);
  __syncthreads();
  #pragma unroll
  for (int q = 0; q < 6; ++q) {
    if (q < 2) {
      const int d = q * 256 + t, r = d >> 5, c = d & 31;
      a4[r * APITCH + c] = rg[q];
    } else {
      const int d2 = (q - 2) * 256 + t, r = d2 >> 5, c = d2 & 31;
      b4[r * APITCH + c] = rg[q];
    }
  }
  __syncthreads();
  computeChunk(32);

  // ---- epilogue ----
  float w3v[8], b2v[8];
  #pragma unroll
  for (int e = 0; e < 8; ++e) { w3v[e] = W3[e]; b2v[e] = b2f[e]; }
  const float b3v = b3[0];
  const int i = i0 + iy;
  #pragma unroll
  for (int jb = 0; jb < 2; ++jb) {
    const int j = j0 + jx + jb * 16;
    if (i < j) {
      const float* af = (const float*)&acc[jb][0];
      float logit = b3v;
      #pragma unroll
      for (int e = 0; e < 8; ++e) {
        const float h2 = fmaxf(af[e] + b2v[e], 0.f);
        logit = fmaf(w3v[e], h2, logit);
      }
      const float score = 1.0f / (1.0f + expf(-logit));
      const int idx = i * 1023 - (i * (i - 1)) / 2 + (j - i - 1);
      out[idx] = score;
      const bool mk = (score > 0.5f) && (stress[i] > smean) && (stress[j] > smean);
      out[P_PAIRS + idx] = mk ? 1.0f : 0.0f;
    }
  }
}

extern "C" void kernel_launch(void* const* d_in, const int* in_sizes, int n_in,
                              void* d_out, int out_size, void* d_ws, size_t ws_size,
                              hipStream_t stream) {
  const float* x     = (const float*)d_in[0];
  const float* ctx   = (const float*)d_in[1];
  const float* W1    = (const float*)d_in[2];
  const float* b1    = (const float*)d_in[3];
  const float* gamma = (const float*)d_in[4];
  const float* beta  = (const float*)d_in[5];
  const float* rmean = (const float*)d_in[6];
  const float* rvar  = (const float*)d_in[7];
  const float* W2    = (const float*)d_in[8];
  const float* b2    = (const float*)d_in[9];
  const float* W3    = (const float*)d_in[10];
  const float* b3    = (const float*)d_in[11];
  float* out = (float*)d_out;

  float* ws     = (float*)d_ws;
  float* pa     = ws;              // 1024*256 (cterm pre-folded)
  float* pb     = pa + 262144;     // 1024*256
  float* w2ft   = pb + 262144;     // 256*8 (transposed [m][e], BN-scaled)
  float* b2f    = w2ft + 2048;     // 8
  float* stress = b2f + 8;         // 1024

  hipLaunchKernelGGL(kA, dim3(257), dim3(256), 0, stream, x, ctx, W1, b1, gamma, beta,
                     rmean, rvar, W2, b2, pa, pb, stress, w2ft, b2f);
  hipLaunchKernelGGL(kC, dim3(NBLK), dim3(256), 0, stream, pa, pb, w2ft, b2f,
                     W3, b3, stress, out);
}